// Round 2
// baseline (3688.108 us; speedup 1.0000x reference)
//
#include <hip/hip_runtime.h>
#include <hip/hip_bf16.h>
#include <math.h>

// Problem constants (B,S,D,H from reference)
#define B_ 4
#define S_ 2048
#define D_ 1024
#define H_ 16
#define HD_ 64
#define TRIPLE (3 * D_) // 3072

// ---------------------------------------------------------------------------
// GEMM: C[M,N] = A[M,K] @ W[N,K]^T + bias[N], optional exact GELU epilogue.
// 128x128 tile, BK=16, 256 threads, each thread 2x2 blocks of 4x4 outputs.
// LDS pad +4 keeps float4 alignment (132*4B = 16B-multiple) and <=2-way banks.
// ---------------------------------------------------------------------------
__device__ __forceinline__ float gelu_f(float x) {
    return 0.5f * x * (1.0f + erff(x * 0.70710678118654752f));
}

__global__ __launch_bounds__(256) void gemm_bias_act(
    const float* __restrict__ A, const float* __restrict__ W,
    const float* __restrict__ bias, float* __restrict__ C,
    int M, int N, int K, int act)
{
    __shared__ float As[16][132]; // [k][m] transposed
    __shared__ float Ws[16][132]; // [k][n] transposed

    const int tid = threadIdx.x;
    const int tx = tid & 15, ty = tid >> 4;
    const int lrow = tid >> 2;          // 0..63
    const int lk = (tid & 3) << 2;      // 0,4,8,12

    const size_t m0 = (size_t)blockIdx.y * 128;
    const size_t n0 = (size_t)blockIdx.x * 128;

    const float* Ap0 = A + (m0 + lrow) * (size_t)K + lk;
    const float* Ap1 = Ap0 + (size_t)64 * K;
    const float* Wp0 = W + (n0 + lrow) * (size_t)K + lk;
    const float* Wp1 = Wp0 + (size_t)64 * K;

    float acc[2][2][4][4] = {};

    for (int k0 = 0; k0 < K; k0 += 16) {
        float4 a0 = *(const float4*)(Ap0 + k0);
        float4 a1 = *(const float4*)(Ap1 + k0);
        float4 w0 = *(const float4*)(Wp0 + k0);
        float4 w1v = *(const float4*)(Wp1 + k0);
        __syncthreads();
        As[lk + 0][lrow] = a0.x; As[lk + 1][lrow] = a0.y;
        As[lk + 2][lrow] = a0.z; As[lk + 3][lrow] = a0.w;
        As[lk + 0][lrow + 64] = a1.x; As[lk + 1][lrow + 64] = a1.y;
        As[lk + 2][lrow + 64] = a1.z; As[lk + 3][lrow + 64] = a1.w;
        Ws[lk + 0][lrow] = w0.x; Ws[lk + 1][lrow] = w0.y;
        Ws[lk + 2][lrow] = w0.z; Ws[lk + 3][lrow] = w0.w;
        Ws[lk + 0][lrow + 64] = w1v.x; Ws[lk + 1][lrow + 64] = w1v.y;
        Ws[lk + 2][lrow + 64] = w1v.z; Ws[lk + 3][lrow + 64] = w1v.w;
        __syncthreads();

        #pragma unroll
        for (int kk = 0; kk < 16; ++kk) {
            float4 av0 = *(const float4*)&As[kk][ty << 2];
            float4 av1 = *(const float4*)&As[kk][(ty << 2) + 64];
            float4 bv0 = *(const float4*)&Ws[kk][tx << 2];
            float4 bv1 = *(const float4*)&Ws[kk][(tx << 2) + 64];
            float ar[2][4] = {{av0.x, av0.y, av0.z, av0.w},
                              {av1.x, av1.y, av1.z, av1.w}};
            float br[2][4] = {{bv0.x, bv0.y, bv0.z, bv0.w},
                              {bv1.x, bv1.y, bv1.z, bv1.w}};
            #pragma unroll
            for (int r = 0; r < 2; ++r)
                #pragma unroll
                for (int c = 0; c < 2; ++c)
                    #pragma unroll
                    for (int i = 0; i < 4; ++i)
                        #pragma unroll
                        for (int j = 0; j < 4; ++j)
                            acc[r][c][i][j] += ar[r][i] * br[c][j];
        }
    }

    #pragma unroll
    for (int r = 0; r < 2; ++r) {
        #pragma unroll
        for (int i = 0; i < 4; ++i) {
            const size_t row = m0 + r * 64 + (ty << 2) + i;
            #pragma unroll
            for (int c = 0; c < 2; ++c) {
                const size_t col = n0 + c * 64 + (tx << 2);
                float4 v;
                v.x = acc[r][c][i][0] + bias[col + 0];
                v.y = acc[r][c][i][1] + bias[col + 1];
                v.z = acc[r][c][i][2] + bias[col + 2];
                v.w = acc[r][c][i][3] + bias[col + 3];
                if (act == 1) {
                    v.x = gelu_f(v.x); v.y = gelu_f(v.y);
                    v.z = gelu_f(v.z); v.w = gelu_f(v.w);
                }
                *(float4*)(C + row * (size_t)N + col) = v;
            }
        }
    }
}

// ---------------------------------------------------------------------------
// Flash-style attention forward: per (b,h) and 64-row q tile, online softmax
// over k tiles of 64. Writes ctx into [B,S,D] head-concat layout and saves
// per-row max (m) and denominator (l) for the attn-weights pass.
// Tile loads: 64 rows x 64 d = 4096 floats = 1024 float4 -> each of the 256
// threads loads 4 consecutive float4 (row = tid>>2, d0 = (tid&3)*16).
// ---------------------------------------------------------------------------
#define F4TOA(arr, v) { arr[0] = (v).x; arr[1] = (v).y; arr[2] = (v).z; arr[3] = (v).w; }

__global__ __launch_bounds__(256) void attn_ctx(
    const float* __restrict__ qkv, float* __restrict__ ctxbuf,
    float* __restrict__ mstat, float* __restrict__ lstat)
{
    __shared__ float Qt[64][68];
    __shared__ float KtP[64][68];
    __shared__ float Vs[64][68];

    const int tid = threadIdx.x;
    const int tx = tid & 15, ty = tid >> 4;
    const int lr = tid >> 2;        // 0..63 (tile row)
    const int ld = (tid & 3) << 4;  // 0,16,32,48 (d chunk start)
    const int bh = blockIdx.y, b = bh >> 4, hh = bh & 15;
    const int q0 = blockIdx.x * 64;

    const float* qbase = qkv + ((size_t)b * S_ + q0) * TRIPLE + hh * HD_;
    const float* kbase = qkv + (size_t)b * S_ * TRIPLE + D_ + hh * HD_;
    const float* vbase = kbase + D_;

    {
        #pragma unroll
        for (int t = 0; t < 4; ++t) {
            float4 q4 = *(const float4*)(qbase + (size_t)lr * TRIPLE + ld + 4 * t);
            Qt[ld + 4 * t + 0][lr] = q4.x;
            Qt[ld + 4 * t + 1][lr] = q4.y;
            Qt[ld + 4 * t + 2][lr] = q4.z;
            Qt[ld + 4 * t + 3][lr] = q4.w;
        }
    }

    float m[4], l[4], o[4][4];
    #pragma unroll
    for (int i = 0; i < 4; ++i) {
        m[i] = -1e30f; l[i] = 0.0f;
        #pragma unroll
        for (int j = 0; j < 4; ++j) o[i][j] = 0.0f;
    }

    for (int k0 = 0; k0 < S_; k0 += 64) {
        float4 k4[4], v4[4];
        #pragma unroll
        for (int t = 0; t < 4; ++t) {
            k4[t] = *(const float4*)(kbase + (size_t)(k0 + lr) * TRIPLE + ld + 4 * t);
            v4[t] = *(const float4*)(vbase + (size_t)(k0 + lr) * TRIPLE + ld + 4 * t);
        }
        __syncthreads(); // previous iteration done reading KtP/Vs
        #pragma unroll
        for (int t = 0; t < 4; ++t) {
            KtP[ld + 4 * t + 0][lr] = k4[t].x;
            KtP[ld + 4 * t + 1][lr] = k4[t].y;
            KtP[ld + 4 * t + 2][lr] = k4[t].z;
            KtP[ld + 4 * t + 3][lr] = k4[t].w;
            *(float4*)&Vs[lr][ld + 4 * t] = v4[t];
        }
        __syncthreads();

        // S tile = Q @ K^T
        float s[4][4] = {};
        #pragma unroll
        for (int d = 0; d < 64; ++d) {
            float4 qv = *(const float4*)&Qt[d][ty << 2];
            float4 kv = *(const float4*)&KtP[d][tx << 2];
            float qa[4]; F4TOA(qa, qv);
            float ka[4]; F4TOA(ka, kv);
            #pragma unroll
            for (int i = 0; i < 4; ++i)
                #pragma unroll
                for (int j = 0; j < 4; ++j)
                    s[i][j] += qa[i] * ka[j];
        }

        // online softmax update (rows live in 16-lane groups)
        float p[4][4];
        #pragma unroll
        for (int i = 0; i < 4; ++i) {
            #pragma unroll
            for (int j = 0; j < 4; ++j) s[i][j] *= 0.125f;
            float tm = fmaxf(fmaxf(s[i][0], s[i][1]), fmaxf(s[i][2], s[i][3]));
            tm = fmaxf(tm, __shfl_xor(tm, 1, 64));
            tm = fmaxf(tm, __shfl_xor(tm, 2, 64));
            tm = fmaxf(tm, __shfl_xor(tm, 4, 64));
            tm = fmaxf(tm, __shfl_xor(tm, 8, 64));
            const float mn = fmaxf(m[i], tm);
            const float al = __expf(m[i] - mn);
            float rs = 0.0f;
            #pragma unroll
            for (int j = 0; j < 4; ++j) { p[i][j] = __expf(s[i][j] - mn); rs += p[i][j]; }
            rs += __shfl_xor(rs, 1, 64);
            rs += __shfl_xor(rs, 2, 64);
            rs += __shfl_xor(rs, 4, 64);
            rs += __shfl_xor(rs, 8, 64);
            l[i] = l[i] * al + rs;
            m[i] = mn;
            #pragma unroll
            for (int j = 0; j < 4; ++j) o[i][j] *= al;
        }

        __syncthreads(); // all GEMM1 reads of KtP done; reuse as P
        #pragma unroll
        for (int i = 0; i < 4; ++i)
            *(float4*)&KtP[(ty << 2) + i][tx << 2] =
                make_float4(p[i][0], p[i][1], p[i][2], p[i][3]);
        __syncthreads();

        // o += P @ V
        #pragma unroll
        for (int kq = 0; kq < 16; ++kq) {
            float pa[4][4];
            #pragma unroll
            for (int i = 0; i < 4; ++i) {
                float4 t = *(const float4*)&KtP[(ty << 2) + i][kq << 2];
                F4TOA(pa[i], t);
            }
            #pragma unroll
            for (int jj = 0; jj < 4; ++jj) {
                float4 tv = *(const float4*)&Vs[(kq << 2) + jj][tx << 2];
                float va[4]; F4TOA(va, tv);
                #pragma unroll
                for (int i = 0; i < 4; ++i)
                    #pragma unroll
                    for (int j = 0; j < 4; ++j)
                        o[i][j] += pa[i][jj] * va[j];
            }
        }
    }

    float inv[4];
    #pragma unroll
    for (int i = 0; i < 4; ++i) inv[i] = 1.0f / l[i];
    #pragma unroll
    for (int i = 0; i < 4; ++i) {
        const int row = q0 + (ty << 2) + i;
        float4 v = make_float4(o[i][0] * inv[i], o[i][1] * inv[i],
                               o[i][2] * inv[i], o[i][3] * inv[i]);
        *(float4*)(ctxbuf + ((size_t)b * S_ + row) * D_ + hh * HD_ + (tx << 2)) = v;
    }
    if (tx == 0) {
        #pragma unroll
        for (int i = 0; i < 4; ++i) {
            const size_t idx = (size_t)bh * S_ + q0 + (ty << 2) + i;
            mstat[idx] = m[i];
            lstat[idx] = l[i];
        }
    }
}

// ---------------------------------------------------------------------------
// Head-averaged attention weights: per (b, q-tile, k-tile), loop all 16 heads,
// recompute the score tile, normalize with saved (m,l), accumulate mean.
// One float4 store per row chunk — no atomics.
// ---------------------------------------------------------------------------
__global__ __launch_bounds__(256) void attn_wts(
    const float* __restrict__ qkv, const float* __restrict__ mstat,
    const float* __restrict__ lstat, float* __restrict__ attnw)
{
    __shared__ float Qt[64][68];
    __shared__ float Kt[64][68];

    const int tid = threadIdx.x;
    const int tx = tid & 15, ty = tid >> 4;
    const int lr = tid >> 2;        // 0..63
    const int ld = (tid & 3) << 4;  // 0,16,32,48
    const int b = blockIdx.z;
    const int q0 = blockIdx.y * 64, k0 = blockIdx.x * 64;

    float wacc[4][4] = {};

    for (int hh = 0; hh < H_; ++hh) {
        const float* qb = qkv + ((size_t)b * S_ + q0) * TRIPLE + hh * HD_;
        const float* kb = qkv + ((size_t)b * S_ + k0) * TRIPLE + D_ + hh * HD_;
        float4 q4[4], k4[4];
        #pragma unroll
        for (int t = 0; t < 4; ++t) {
            q4[t] = *(const float4*)(qb + (size_t)lr * TRIPLE + ld + 4 * t);
            k4[t] = *(const float4*)(kb + (size_t)lr * TRIPLE + ld + 4 * t);
        }
        __syncthreads();
        #pragma unroll
        for (int t = 0; t < 4; ++t) {
            Qt[ld + 4 * t + 0][lr] = q4[t].x;
            Qt[ld + 4 * t + 1][lr] = q4[t].y;
            Qt[ld + 4 * t + 2][lr] = q4[t].z;
            Qt[ld + 4 * t + 3][lr] = q4[t].w;
            Kt[ld + 4 * t + 0][lr] = k4[t].x;
            Kt[ld + 4 * t + 1][lr] = k4[t].y;
            Kt[ld + 4 * t + 2][lr] = k4[t].z;
            Kt[ld + 4 * t + 3][lr] = k4[t].w;
        }
        __syncthreads();

        float s[4][4] = {};
        #pragma unroll
        for (int d = 0; d < 64; ++d) {
            float4 qv = *(const float4*)&Qt[d][ty << 2];
            float4 kv = *(const float4*)&Kt[d][tx << 2];
            float qa[4]; F4TOA(qa, qv);
            float ka[4]; F4TOA(ka, kv);
            #pragma unroll
            for (int i = 0; i < 4; ++i)
                #pragma unroll
                for (int j = 0; j < 4; ++j)
                    s[i][j] += qa[i] * ka[j];
        }

        const float* mp = mstat + ((size_t)(b * H_ + hh)) * S_ + q0 + (ty << 2);
        const float* lp = lstat + ((size_t)(b * H_ + hh)) * S_ + q0 + (ty << 2);
        #pragma unroll
        for (int i = 0; i < 4; ++i) {
            const float mi = mp[i];
            const float il = 1.0f / lp[i];
            #pragma unroll
            for (int j = 0; j < 4; ++j)
                wacc[i][j] += __expf(s[i][j] * 0.125f - mi) * il;
        }
    }

    const float invH = 1.0f / (float)H_;
    #pragma unroll
    for (int i = 0; i < 4; ++i) {
        const int row = q0 + (ty << 2) + i;
        float4 v = make_float4(wacc[i][0] * invH, wacc[i][1] * invH,
                               wacc[i][2] * invH, wacc[i][3] * invH);
        *(float4*)(attnw + (size_t)b * S_ * S_ + (size_t)row * S_ + k0 + (tx << 2)) = v;
    }
}

// ---------------------------------------------------------------------------
// Fused residual-add + LayerNorm over D=1024. One block (256 thr) per row,
// float4 per thread, wave shfl + LDS cross-wave reduction.
// ---------------------------------------------------------------------------
__global__ __launch_bounds__(256) void ln_resid(
    const float* __restrict__ xin, const float* __restrict__ resid,
    const float* __restrict__ g, const float* __restrict__ bb,
    float* __restrict__ outp)
{
    const int row = blockIdx.x, tid = threadIdx.x;
    const size_t off = (size_t)row * D_ + (tid << 2);
    float4 a = *(const float4*)(xin + off);
    float4 r = *(const float4*)(resid + off);
    float v[4] = {a.x + r.x, a.y + r.y, a.z + r.z, a.w + r.w};
    float sum = v[0] + v[1] + v[2] + v[3];
    float ssq = v[0]*v[0] + v[1]*v[1] + v[2]*v[2] + v[3]*v[3];
    #pragma unroll
    for (int msk = 1; msk < 64; msk <<= 1) {
        sum += __shfl_xor(sum, msk, 64);
        ssq += __shfl_xor(ssq, msk, 64);
    }
    __shared__ float red[8];
    const int wv = tid >> 6, ln_ = tid & 63;
    if (ln_ == 0) { red[wv] = sum; red[4 + wv] = ssq; }
    __syncthreads();
    sum = red[0] + red[1] + red[2] + red[3];
    ssq = red[4] + red[5] + red[6] + red[7];
    const float mu = sum * (1.0f / D_);
    const float var = ssq * (1.0f / D_) - mu * mu;
    const float rstd = rsqrtf(var + 1e-5f);
    float4 gv = *(const float4*)(g + (tid << 2));
    float4 bv = *(const float4*)(bb + (tid << 2));
    float4 o;
    o.x = (v[0] - mu) * rstd * gv.x + bv.x;
    o.y = (v[1] - mu) * rstd * gv.y + bv.y;
    o.z = (v[2] - mu) * rstd * gv.z + bv.z;
    o.w = (v[3] - mu) * rstd * gv.w + bv.w;
    *(float4*)(outp + off) = o;
}

// ---------------------------------------------------------------------------
extern "C" void kernel_launch(void* const* d_in, const int* in_sizes, int n_in,
                              void* d_out, int out_size, void* d_ws, size_t ws_size,
                              hipStream_t stream)
{
    (void)in_sizes; (void)n_in; (void)out_size; (void)ws_size;
    const float* x    = (const float*)d_in[0];
    const float* wqkv = (const float*)d_in[1];
    const float* bqkv = (const float*)d_in[2];
    const float* wo   = (const float*)d_in[3];
    const float* bo   = (const float*)d_in[4];
    const float* lng  = (const float*)d_in[5];
    const float* lnb  = (const float*)d_in[6];
    const float* w1   = (const float*)d_in[7];
    const float* b1   = (const float*)d_in[8];
    const float* w2   = (const float*)d_in[9];
    const float* b2   = (const float*)d_in[10];

    float* outp  = (float*)d_out;
    float* attnw = outp + (size_t)B_ * S_ * D_;

    // workspace layout (floats):
    // qkv: B*S*3D (96 MiB) | ctx: B*S*D | attended: B*S*D | h: B*S*D
    // mstat/lstat: B*H*S each.  ff1/ff2 reuse the (dead) qkv region.
    float* ws   = (float*)d_ws;
    float* qkv  = ws;
    float* ctx  = qkv + (size_t)B_ * S_ * TRIPLE;
    float* attd = ctx + (size_t)B_ * S_ * D_;
    float* hbuf = attd + (size_t)B_ * S_ * D_;
    float* mst  = hbuf + (size_t)B_ * S_ * D_;
    float* lst  = mst + (size_t)B_ * H_ * S_;
    float* ff1  = qkv;                                   // B*S*2D
    float* ff2  = qkv + (size_t)B_ * S_ * (2 * D_);      // B*S*D

    const int M = B_ * S_; // 8192
    dim3 blk(256);

    // 1. QKV projection: [M,3072] = x @ wqkv^T + bqkv
    gemm_bias_act<<<dim3(TRIPLE / 128, M / 128), blk, 0, stream>>>(
        x, wqkv, bqkv, qkv, M, TRIPLE, D_, 0);
    // 2. attention ctx + softmax stats
    attn_ctx<<<dim3(S_ / 64, B_ * H_), blk, 0, stream>>>(qkv, ctx, mst, lst);
    // 3. head-averaged attention weights
    attn_wts<<<dim3(S_ / 64, S_ / 64, B_), blk, 0, stream>>>(qkv, mst, lst, attnw);
    // 4. out projection
    gemm_bias_act<<<dim3(D_ / 128, M / 128), blk, 0, stream>>>(
        ctx, wo, bo, attd, M, D_, D_, 0);
    // 5. LN1: h = LN(attended + x)
    ln_resid<<<dim3(M), blk, 0, stream>>>(attd, x, lng, lnb, hbuf);
    // 6. FF1 + GELU: [M,2048]
    gemm_bias_act<<<dim3((2 * D_) / 128, M / 128), blk, 0, stream>>>(
        hbuf, w1, b1, ff1, M, 2 * D_, D_, 1);
    // 7. FF2: [M,1024]
    gemm_bias_act<<<dim3(D_ / 128, M / 128), blk, 0, stream>>>(
        ff1, w2, b2, ff2, M, D_, 2 * D_, 0);
    // 8. LN2: out = LN(ff2 + h)
    ln_resid<<<dim3(M), blk, 0, stream>>>(ff2, hbuf, lng, lnb, outp);
}

// Round 7
// 725.950 us; speedup vs baseline: 5.0804x; 5.0804x over previous
//
#include <hip/hip_runtime.h>
#include <hip/hip_bf16.h>
#include <math.h>

#define B_ 4
#define S_ 2048
#define D_ 1024
#define H_ 16
#define HD_ 64
#define TRIPLE 3072

typedef __attribute__((ext_vector_type(8))) short bf16x8;
typedef __attribute__((ext_vector_type(4))) float f32x4;
typedef __attribute__((ext_vector_type(8))) unsigned short u16x8;
typedef unsigned short ushort_t;

#define MFMA(a, b, c) __builtin_amdgcn_mfma_f32_16x16x32_bf16((a), (b), (c), 0, 0, 0)

__device__ __forceinline__ ushort_t f2bf(float f) {
    union { float f; unsigned int u; } u; u.f = f;
    unsigned int r = u.u + 0x7fff + ((u.u >> 16) & 1); // RNE
    return (ushort_t)(r >> 16);
}
__device__ __forceinline__ float bf2f(ushort_t h) {
    union { unsigned int u; float f; } u; u.u = ((unsigned int)h) << 16;
    return u.f;
}

// ---------------------------------------------------------------------------
// fp32 -> bf16 cast, 8 elems/thread
// ---------------------------------------------------------------------------
__global__ __launch_bounds__(256) void castk(const float* __restrict__ s,
                                             ushort_t* __restrict__ d, int n) {
    int i = (blockIdx.x * 256 + threadIdx.x) * 8;
    if (i >= n) return;
    float4 a = *(const float4*)(s + i);
    float4 b = *(const float4*)(s + i + 4);
    u16x8 o;
    o[0] = f2bf(a.x); o[1] = f2bf(a.y); o[2] = f2bf(a.z); o[3] = f2bf(a.w);
    o[4] = f2bf(b.x); o[5] = f2bf(b.y); o[6] = f2bf(b.z); o[7] = f2bf(b.w);
    *(u16x8*)(d + i) = o;
}

// ---------------------------------------------------------------------------
// BF16 MFMA GEMM: C[M,N] = A[M,K] @ W[N,K]^T + bias, optional exact GELU.
// 128x128 tile, BK=64, 4 waves (2x2 of 64x64), 16x16x32 MFMA.
// LDS rows 128B, slot-XOR swizzle (slot ^ (row&7)) for balanced ds_read_b128.
// M fixed = 8192 (grid.y = 64).
// ---------------------------------------------------------------------------
__global__ __launch_bounds__(256) void gemm_bf16(
    const ushort_t* __restrict__ A, const ushort_t* __restrict__ W,
    const float* __restrict__ bias, ushort_t* __restrict__ C,
    int N, int K, int act)
{
    __shared__ char Asb[128 * 128];
    __shared__ char Wsb[128 * 128];
    const int tid = threadIdx.x;
    const int wv = tid >> 6, lane = tid & 63;
    const int fr = lane & 15, fq = lane >> 4;
    const int wr = wv >> 1, wc = wv & 1;
    const int m0 = blockIdx.y * 128, n0 = blockIdx.x * 128;
    const int srow = tid >> 1, sh = tid & 1;

    const ushort_t* Ag = A + (size_t)(m0 + srow) * K + sh * 32;
    const ushort_t* Wg = W + (size_t)(n0 + srow) * K + sh * 32;
    const int swb = srow * 128;
    const int sxr = srow & 7;
    const int fx = fr & 7;

    const f32x4 fz = {0.f, 0.f, 0.f, 0.f};
    f32x4 acc[4][4];
    #pragma unroll
    for (int i = 0; i < 4; ++i)
        #pragma unroll
        for (int j = 0; j < 4; ++j) acc[i][j] = fz;

    for (int k0 = 0; k0 < K; k0 += 64) {
        u16x8 av[4], wvv[4];
        #pragma unroll
        for (int c = 0; c < 4; ++c) {
            av[c] = *(const u16x8*)(Ag + k0 + c * 8);
            wvv[c] = *(const u16x8*)(Wg + k0 + c * 8);
        }
        __syncthreads();
        #pragma unroll
        for (int c = 0; c < 4; ++c) {
            int slot = (sh * 4 + c) ^ sxr;
            *(u16x8*)(Asb + swb + slot * 16) = av[c];
            *(u16x8*)(Wsb + swb + slot * 16) = wvv[c];
        }
        __syncthreads();
        #pragma unroll
        for (int ks = 0; ks < 2; ++ks) {
            bf16x8 af[4], bfr[4];
            #pragma unroll
            for (int i = 0; i < 4; ++i) {
                int ra = wr * 64 + i * 16 + fr;
                int rb = wc * 64 + i * 16 + fr;
                int slot = (ks * 4 + fq) ^ fx;
                af[i] = *(const bf16x8*)(Asb + ra * 128 + slot * 16);
                bfr[i] = *(const bf16x8*)(Wsb + rb * 128 + slot * 16);
            }
            #pragma unroll
            for (int i = 0; i < 4; ++i)
                #pragma unroll
                for (int j = 0; j < 4; ++j)
                    acc[i][j] = MFMA(af[i], bfr[j], acc[i][j]);
        }
    }

    float bv[4];
    #pragma unroll
    for (int j = 0; j < 4; ++j) bv[j] = bias[n0 + wc * 64 + j * 16 + fr];
    #pragma unroll
    for (int i = 0; i < 4; ++i) {
        #pragma unroll
        for (int j = 0; j < 4; ++j) {
            int col = n0 + wc * 64 + j * 16 + fr;
            #pragma unroll
            for (int r = 0; r < 4; ++r) {
                int row = m0 + wr * 64 + i * 16 + fq * 4 + r;
                float v = acc[i][j][r] + bv[j];
                if (act) v = 0.5f * v * (1.0f + erff(v * 0.70710678118654752f));
                C[(size_t)row * N + col] = f2bf(v);
            }
        }
    }
}

// ---------------------------------------------------------------------------
// V transpose: qkv bf16 [B,S,3D] V-part -> vT [B*H, 64, S] bf16.
// ---------------------------------------------------------------------------
__global__ __launch_bounds__(256) void vtrans(const ushort_t* __restrict__ qkvb,
                                              ushort_t* __restrict__ vT)
{
    __shared__ ushort_t T[64][72];
    const int tid = threadIdx.x;
    const int bh = blockIdx.y;
    const int b = bh >> 4, h = bh & 15;
    const int s0 = blockIdx.x * 64;
    const int r = tid >> 2, q = tid & 3;
    const ushort_t* src = qkvb + (size_t)(b * S_ + s0 + r) * TRIPLE + 2048 + h * 64 + q * 16;
    *(u16x8*)&T[r][q * 16] = *(const u16x8*)(src);
    *(u16x8*)&T[r][q * 16 + 8] = *(const u16x8*)(src + 8);
    __syncthreads();
    u16x8 o0, o1;
    #pragma unroll
    for (int i = 0; i < 8; ++i) o0[i] = T[q * 16 + i][r];
    #pragma unroll
    for (int i = 0; i < 8; ++i) o1[i] = T[q * 16 + 8 + i][r];
    ushort_t* dstp = vT + ((size_t)bh * 64 + r) * S_ + s0 + q * 16;
    *(u16x8*)(dstp) = o0;
    *(u16x8*)(dstp + 8) = o1;
}

// ---------------------------------------------------------------------------
// Flash attention (MFMA): block = (q-tile 64, b*h). 4 waves, each 16 q-rows.
// K (natural) + V^T staged in swizzled LDS; Q in registers; online softmax;
// P bf16 in wave-private LDS rows; PV via MFMA. Outputs ctx bf16 + (m,l).
// ---------------------------------------------------------------------------
__global__ __launch_bounds__(256) void attn_ctx_mfma(
    const ushort_t* __restrict__ qkvb, const ushort_t* __restrict__ vT,
    ushort_t* __restrict__ ctxb, float* __restrict__ mstat, float* __restrict__ lstat)
{
    __shared__ char Kl[64 * 128];
    __shared__ char Vl[64 * 128];
    __shared__ char Pl[64 * 128];
    const int tid = threadIdx.x;
    const int wv = tid >> 6, lane = tid & 63;
    const int fr = lane & 15, fq = lane >> 4;
    const int fx = fr & 7;
    const int bh = blockIdx.y, b = bh >> 4, h = bh & 15;
    const int q0 = blockIdx.x * 64;

    bf16x8 qf[2];
    {
        const ushort_t* qp = qkvb + (size_t)(b * S_ + q0 + wv * 16 + fr) * TRIPLE + h * 64 + fq * 8;
        qf[0] = *(const bf16x8*)(qp);
        qf[1] = *(const bf16x8*)(qp + 32);
    }

    const int srow = tid >> 2, sq = tid & 3;
    const ushort_t* Kg = qkvb + (size_t)(b * S_ + srow) * TRIPLE + 1024 + h * 64 + sq * 16;
    const ushort_t* Vg = vT + ((size_t)bh * 64 + srow) * S_ + sq * 16;
    const int sb = srow * 128, sxr = srow & 7;
    const int slot0 = (sq * 2) ^ sxr, slot1 = (sq * 2 + 1) ^ sxr;

    const f32x4 fz = {0.f, 0.f, 0.f, 0.f};
    float m_[4], l_[4];
    f32x4 po[4];
    #pragma unroll
    for (int r = 0; r < 4; ++r) { m_[r] = -1e30f; l_[r] = 0.f; }
    #pragma unroll
    for (int dn = 0; dn < 4; ++dn) po[dn] = fz;

    for (int k0 = 0; k0 < S_; k0 += 64) {
        u16x8 ks0 = *(const u16x8*)(Kg + (size_t)k0 * TRIPLE);
        u16x8 ks1 = *(const u16x8*)(Kg + (size_t)k0 * TRIPLE + 8);
        u16x8 vs0 = *(const u16x8*)(Vg + k0);
        u16x8 vs1 = *(const u16x8*)(Vg + k0 + 8);
        __syncthreads();
        *(u16x8*)(Kl + sb + slot0 * 16) = ks0;
        *(u16x8*)(Kl + sb + slot1 * 16) = ks1;
        *(u16x8*)(Vl + sb + slot0 * 16) = vs0;
        *(u16x8*)(Vl + sb + slot1 * 16) = vs1;
        __syncthreads();

        // S = Q K^T (rows wv*16..+16)
        f32x4 sa[4];
        #pragma unroll
        for (int jn = 0; jn < 4; ++jn) sa[jn] = fz;
        #pragma unroll
        for (int ks = 0; ks < 2; ++ks) {
            #pragma unroll
            for (int jn = 0; jn < 4; ++jn) {
                int kr = jn * 16 + fr;
                bf16x8 kf = *(const bf16x8*)(Kl + kr * 128 + (((ks * 4 + fq) ^ fx) * 16));
                sa[jn] = MFMA(qf[ks], kf, sa[jn]);
            }
        }

        // online softmax (row q = wv*16 + fq*4 + r; kv spread over fr within jn)
        float p[4][4], al[4];
        #pragma unroll
        for (int r = 0; r < 4; ++r) {
            float s0v = sa[0][r] * 0.125f, s1v = sa[1][r] * 0.125f;
            float s2v = sa[2][r] * 0.125f, s3v = sa[3][r] * 0.125f;
            float tm = fmaxf(fmaxf(s0v, s1v), fmaxf(s2v, s3v));
            tm = fmaxf(tm, __shfl_xor(tm, 1));
            tm = fmaxf(tm, __shfl_xor(tm, 2));
            tm = fmaxf(tm, __shfl_xor(tm, 4));
            tm = fmaxf(tm, __shfl_xor(tm, 8));
            float mn = fmaxf(m_[r], tm);
            al[r] = __expf(m_[r] - mn);
            p[0][r] = __expf(s0v - mn); p[1][r] = __expf(s1v - mn);
            p[2][r] = __expf(s2v - mn); p[3][r] = __expf(s3v - mn);
            float rs = p[0][r] + p[1][r] + p[2][r] + p[3][r];
            rs += __shfl_xor(rs, 1); rs += __shfl_xor(rs, 2);
            rs += __shfl_xor(rs, 4); rs += __shfl_xor(rs, 8);
            l_[r] = l_[r] * al[r] + rs;
            m_[r] = mn;
        }
        #pragma unroll
        for (int dn = 0; dn < 4; ++dn)
            #pragma unroll
            for (int r = 0; r < 4; ++r) po[dn][r] *= al[r];

        // write P (bf16) to wave-private rows
        #pragma unroll
        for (int jn = 0; jn < 4; ++jn) {
            int kvslot = jn * 2 + (fr >> 3);
            #pragma unroll
            for (int r = 0; r < 4; ++r) {
                int qq = wv * 16 + fq * 4 + r;
                *(ushort_t*)(Pl + qq * 128 + ((kvslot ^ (qq & 7)) << 4) + (fr & 7) * 2) = f2bf(p[jn][r]);
            }
        }

        // O += P V  (A = P rows wv*16+fr, B = V^T)
        const int qrow = wv * 16 + fr;
        #pragma unroll
        for (int ks = 0; ks < 2; ++ks) {
            bf16x8 pf = *(const bf16x8*)(Pl + qrow * 128 + (((ks * 4 + fq) ^ fx) * 16));
            #pragma unroll
            for (int dn = 0; dn < 4; ++dn) {
                int dr = dn * 16 + fr;
                bf16x8 vf = *(const bf16x8*)(Vl + dr * 128 + (((ks * 4 + fq) ^ fx) * 16));
                po[dn] = MFMA(pf, vf, po[dn]);
            }
        }
    }

    if (fr == 0) {
        #pragma unroll
        for (int r = 0; r < 4; ++r) {
            size_t idx = (size_t)bh * S_ + q0 + wv * 16 + fq * 4 + r;
            mstat[idx] = m_[r];
            lstat[idx] = l_[r];
        }
    }
    float inv[4];
    #pragma unroll
    for (int r = 0; r < 4; ++r) inv[r] = 1.0f / l_[r];
    #pragma unroll
    for (int dn = 0; dn < 4; ++dn) {
        int col = h * 64 + dn * 16 + fr;
        #pragma unroll
        for (int r = 0; r < 4; ++r) {
            int row = q0 + wv * 16 + fq * 4 + r;
            ctxb[(size_t)(b * S_ + row) * D_ + col] = f2bf(po[dn][r] * inv[r]);
        }
    }
}

// ---------------------------------------------------------------------------
// Head-averaged attn weights: block = (k-tile, q-tile, b). Loop 16 heads,
// MFMA score tile (bit-identical accumulation order to attn_ctx), normalize
// with saved (m,l), accumulate mean, one fp32 store per element.
// ---------------------------------------------------------------------------
__global__ __launch_bounds__(256) void attn_wts_mfma(
    const ushort_t* __restrict__ qkvb, const float* __restrict__ mstat,
    const float* __restrict__ lstat, float* __restrict__ attnw)
{
    __shared__ char Ql[64 * 128];
    __shared__ char Kl[64 * 128];
    const int tid = threadIdx.x;
    const int wv = tid >> 6, lane = tid & 63;
    const int fr = lane & 15, fq = lane >> 4;
    const int fx = fr & 7;
    const int b = blockIdx.z;
    const int q0 = blockIdx.y * 64, k0 = blockIdx.x * 64;
    const int srow = tid >> 2, sq = tid & 3;
    const int sb = srow * 128, sxr = srow & 7;
    const int slot0 = (sq * 2) ^ sxr, slot1 = (sq * 2 + 1) ^ sxr;

    const f32x4 fz = {0.f, 0.f, 0.f, 0.f};
    float wacc[4][4];
    #pragma unroll
    for (int jn = 0; jn < 4; ++jn)
        #pragma unroll
        for (int r = 0; r < 4; ++r) wacc[jn][r] = 0.f;

    for (int h = 0; h < H_; ++h) {
        const ushort_t* Qg = qkvb + (size_t)(b * S_ + q0 + srow) * TRIPLE + h * 64 + sq * 16;
        const ushort_t* Kg = qkvb + (size_t)(b * S_ + k0 + srow) * TRIPLE + 1024 + h * 64 + sq * 16;
        u16x8 qv0 = *(const u16x8*)(Qg);
        u16x8 qv1 = *(const u16x8*)(Qg + 8);
        u16x8 kv0 = *(const u16x8*)(Kg);
        u16x8 kv1 = *(const u16x8*)(Kg + 8);
        __syncthreads();
        *(u16x8*)(Ql + sb + slot0 * 16) = qv0;
        *(u16x8*)(Ql + sb + slot1 * 16) = qv1;
        *(u16x8*)(Kl + sb + slot0 * 16) = kv0;
        *(u16x8*)(Kl + sb + slot1 * 16) = kv1;
        __syncthreads();

        f32x4 sa[4];
        #pragma unroll
        for (int jn = 0; jn < 4; ++jn) sa[jn] = fz;
        const int qrow = wv * 16 + fr;
        #pragma unroll
        for (int ks = 0; ks < 2; ++ks) {
            bf16x8 qfr = *(const bf16x8*)(Ql + qrow * 128 + (((ks * 4 + fq) ^ fx) * 16));
            #pragma unroll
            for (int jn = 0; jn < 4; ++jn) {
                int kr = jn * 16 + fr;
                bf16x8 kf = *(const bf16x8*)(Kl + kr * 128 + (((ks * 4 + fq) ^ fx) * 16));
                sa[jn] = MFMA(qfr, kf, sa[jn]);
            }
        }

        const float* mp = mstat + (size_t)(b * H_ + h) * S_ + q0 + wv * 16 + fq * 4;
        const float* lp = lstat + (size_t)(b * H_ + h) * S_ + q0 + wv * 16 + fq * 4;
        #pragma unroll
        for (int r = 0; r < 4; ++r) {
            float mi = mp[r], il = 1.0f / lp[r];
            #pragma unroll
            for (int jn = 0; jn < 4; ++jn)
                wacc[jn][r] += __expf(sa[jn][r] * 0.125f - mi) * il;
        }
    }

    #pragma unroll
    for (int jn = 0; jn < 4; ++jn) {
        #pragma unroll
        for (int r = 0; r < 4; ++r) {
            int row = q0 + wv * 16 + fq * 4 + r;
            attnw[(size_t)b * S_ * S_ + (size_t)row * S_ + k0 + jn * 16 + fr] =
                wacc[jn][r] * 0.0625f;
        }
    }
}

// ---------------------------------------------------------------------------
// Residual-add + LayerNorm: main input bf16, residual fp32; out fp32 (+bf16).
// ---------------------------------------------------------------------------
__global__ __launch_bounds__(256) void ln_kernel(
    const ushort_t* __restrict__ xin_bf, const float* __restrict__ resid,
    const float* __restrict__ g, const float* __restrict__ bb,
    float* __restrict__ out_f32, ushort_t* __restrict__ out_bf, int write_bf)
{
    const int row = blockIdx.x, tid = threadIdx.x;
    const size_t off = (size_t)row * D_ + tid * 4;
    union { uint2 u2; ushort_t hx[4]; } uu;
    uu.u2 = *(const uint2*)(xin_bf + off);
    float4 rr = *(const float4*)(resid + off);
    float v[4];
    v[0] = bf2f(uu.hx[0]) + rr.x; v[1] = bf2f(uu.hx[1]) + rr.y;
    v[2] = bf2f(uu.hx[2]) + rr.z; v[3] = bf2f(uu.hx[3]) + rr.w;
    float sum = v[0] + v[1] + v[2] + v[3];
    float ssq = v[0]*v[0] + v[1]*v[1] + v[2]*v[2] + v[3]*v[3];
    #pragma unroll
    for (int msk = 1; msk < 64; msk <<= 1) {
        sum += __shfl_xor(sum, msk);
        ssq += __shfl_xor(ssq, msk);
    }
    __shared__ float red[8];
    const int wvi = tid >> 6, ln_ = tid & 63;
    if (ln_ == 0) { red[wvi] = sum; red[4 + wvi] = ssq; }
    __syncthreads();
    sum = red[0] + red[1] + red[2] + red[3];
    ssq = red[4] + red[5] + red[6] + red[7];
    const float mu = sum * (1.0f / D_);
    const float var = ssq * (1.0f / D_) - mu * mu;
    const float rstd = rsqrtf(var + 1e-5f);
    float4 gv = *(const float4*)(g + tid * 4);
    float4 bv = *(const float4*)(bb + tid * 4);
    float o0 = (v[0] - mu) * rstd * gv.x + bv.x;
    float o1 = (v[1] - mu) * rstd * gv.y + bv.y;
    float o2 = (v[2] - mu) * rstd * gv.z + bv.z;
    float o3 = (v[3] - mu) * rstd * gv.w + bv.w;
    *(float4*)(out_f32 + off) = make_float4(o0, o1, o2, o3);
    if (write_bf) {
        union { uint2 u2; ushort_t hx[4]; } ob;
        ob.hx[0] = f2bf(o0); ob.hx[1] = f2bf(o1);
        ob.hx[2] = f2bf(o2); ob.hx[3] = f2bf(o3);
        *(uint2*)(out_bf + off) = ob.u2;
    }
}

// ---------------------------------------------------------------------------
extern "C" void kernel_launch(void* const* d_in, const int* in_sizes, int n_in,
                              void* d_out, int out_size, void* d_ws, size_t ws_size,
                              hipStream_t stream)
{
    (void)in_sizes; (void)n_in; (void)out_size; (void)ws_size;
    const float* x    = (const float*)d_in[0];
    const float* wqkv = (const float*)d_in[1];
    const float* bqkv = (const float*)d_in[2];
    const float* wo   = (const float*)d_in[3];
    const float* bo   = (const float*)d_in[4];
    const float* lng  = (const float*)d_in[5];
    const float* lnb  = (const float*)d_in[6];
    const float* w1   = (const float*)d_in[7];
    const float* b1   = (const float*)d_in[8];
    const float* w2   = (const float*)d_in[9];
    const float* b2   = (const float*)d_in[10];

    float* outp  = (float*)d_out;
    float* attnw = outp + (size_t)B_ * S_ * D_;

    // workspace layout (bytes), 193 MiB total:
    // 0: qkvb 48M | 48M: vT/ff2b 16M | 64M: ctxb 16M | 80M: attdb 16M
    // 96M: h_f32 32M | 128M: h_bf16 16M | 144M: xb/ff1b 32M
    // 176M: weights 16M | 192M: mst/lst 1M
    char* wsb = (char*)d_ws;
    ushort_t* qkvb  = (ushort_t*)(wsb);
    ushort_t* vT    = (ushort_t*)(wsb + ((size_t)48 << 20));
    ushort_t* ff2b  = vT;
    ushort_t* ctxb  = (ushort_t*)(wsb + ((size_t)64 << 20));
    ushort_t* attdb = (ushort_t*)(wsb + ((size_t)80 << 20));
    float*    hf    = (float*)(wsb + ((size_t)96 << 20));
    ushort_t* hbf   = (ushort_t*)(wsb + ((size_t)128 << 20));
    ushort_t* xb    = (ushort_t*)(wsb + ((size_t)144 << 20));
    ushort_t* ff1b  = xb;
    ushort_t* wqkvb = (ushort_t*)(wsb + ((size_t)176 << 20));
    ushort_t* wob   = (ushort_t*)(wsb + ((size_t)182 << 20));
    ushort_t* w1b   = (ushort_t*)(wsb + ((size_t)184 << 20));
    ushort_t* w2b   = (ushort_t*)(wsb + ((size_t)188 << 20));
    float*    mst   = (float*)(wsb + ((size_t)192 << 20));
    float*    lst   = (float*)(wsb + ((size_t)192 << 20) + ((size_t)512 << 10));

    dim3 blk(256);

    // 0. casts
    castk<<<dim3(8388608 / 2048), blk, 0, stream>>>(x, xb, 8388608);
    castk<<<dim3(3145728 / 2048), blk, 0, stream>>>(wqkv, wqkvb, 3145728);
    castk<<<dim3(1048576 / 2048), blk, 0, stream>>>(wo, wob, 1048576);
    castk<<<dim3(2097152 / 2048), blk, 0, stream>>>(w1, w1b, 2097152);
    castk<<<dim3(2097152 / 2048), blk, 0, stream>>>(w2, w2b, 2097152);

    // 1. QKV projection
    gemm_bf16<<<dim3(24, 64), blk, 0, stream>>>(xb, wqkvb, bqkv, qkvb, 3072, 1024, 0);
    // 2. V transpose
    vtrans<<<dim3(32, 64), blk, 0, stream>>>(qkvb, vT);
    // 3. attention ctx + stats
    attn_ctx_mfma<<<dim3(32, 64), blk, 0, stream>>>(qkvb, vT, ctxb, mst, lst);
    // 4. head-averaged attention weights
    attn_wts_mfma<<<dim3(32, 32, 4), blk, 0, stream>>>(qkvb, mst, lst, attnw);
    // 5. out projection
    gemm_bf16<<<dim3(8, 64), blk, 0, stream>>>(ctxb, wob, bo, attdb, 1024, 1024, 0);
    // 6. LN1
    ln_kernel<<<dim3(8192), blk, 0, stream>>>(attdb, x, lng, lnb, hf, hbf, 1);
    // 7. FF1 + GELU
    gemm_bf16<<<dim3(16, 64), blk, 0, stream>>>(hbf, w1b, b1, ff1b, 2048, 1024, 1);
    // 8. FF2
    gemm_bf16<<<dim3(8, 64), blk, 0, stream>>>(ff1b, w2b, b2, ff2b, 1024, 2048, 0);
    // 9. LN2 -> final out
    ln_kernel<<<dim3(8192), blk, 0, stream>>>(ff2b, hf, lng, lnb, outp, (ushort_t*)0, 0);
}